// Round 19
// baseline (159.315 us; speedup 1.0000x reference)
//
#include <hip/hip_runtime.h>

typedef short bf16x8 __attribute__((ext_vector_type(8)));
typedef float f32x4 __attribute__((ext_vector_type(4)));
typedef unsigned short us8 __attribute__((ext_vector_type(8)));

__device__ __forceinline__ unsigned short f2bf(float f) {
    unsigned int u = __float_as_uint(f);
    u += 0x7fffu + ((u >> 16) & 1u);   // round-to-nearest-even
    return (unsigned short)(u >> 16);
}
__device__ __forceinline__ float bf2f(unsigned short s) {
    return __uint_as_float((unsigned int)s << 16);
}

// raw barrier: does NOT drain vmcnt (in-flight global->VGPR loads survive);
// lgkmcnt(0) makes ds_writes visible; sched_barrier pins ordering (rule #18).
__device__ __forceinline__ void hard_barrier() {
    asm volatile("s_waitcnt lgkmcnt(0)" ::: "memory");
    __builtin_amdgcn_sched_barrier(0);
    __builtin_amdgcn_s_barrier();
    __builtin_amdgcn_sched_barrier(0);
}

// ---- transpose + cast fp32 -> bf16: body shared by the merged launcher ----
__device__ __forceinline__ void transpose_tile(
    const float* __restrict__ in, unsigned short* __restrict__ out,
    int R, int Cc, int r0, int c0, int t) {
    __shared__ alignas(16) unsigned short sT[64][65];
#pragma unroll
    for (int p = 0; p < 16; ++p) {
        int flat = p * 256 + t;
        int r = flat >> 6, c = flat & 63;
        sT[c][r] = f2bf(in[(size_t)(r0 + r) * Cc + (c0 + c)]);
    }
    __syncthreads();
#pragma unroll
    for (int p = 0; p < 16; ++p) {
        int flat = p * 256 + t;
        int c = flat >> 6, r = flat & 63;
        out[(size_t)(c0 + c) * R + (r0 + r)] = sT[c][r];
    }
}

// one launch transposes both W1 (256x256, 16 tiles) and W2 (256x64, 4 tiles)
__global__ __launch_bounds__(256) void transpose2_kernel(
    const float* __restrict__ W1, const float* __restrict__ W2,
    unsigned short* __restrict__ W1T, unsigned short* __restrict__ W2T) {
    const int bx = blockIdx.x, t = threadIdx.x;
    if (bx < 16) transpose_tile(W1, W1T, 256, 256, (bx & 3) * 64, (bx >> 2) * 64, t);
    else         transpose_tile(W2, W2T, 256, 64, (bx - 16) * 64, 0, t);
}

// ---- small MFMA GEMM (templated BM, 4 waves): C[M][N] = A[M][K] @ BT^T ----
// AMODE 1: A fp32 -> bf16 during staging.
// AMODE 4: A = relu(sum of 4 bf16 slabs, stride aslab elems) -> bf16 staging.
// TOUT: write bf16 transposed C[N][M].
// BM=32 -> grid 256 blocks = full chip (R18 lesson).
template<int BM, int BN, int WM, int WN, int AMODE, bool TOUT, typename OutT>
__global__ __launch_bounds__(256) void gemm_kernel(
    const void* __restrict__ Aptr, const unsigned short* __restrict__ BT,
    OutT* __restrict__ C, int M, int N, int K, long aslab) {
    constexpr int BK = 64, LDW = 72;
    constexpr int MF = BM / WM / 16;
    constexpr int NF = BN / WN / 16;
    constexpr int AP1 = BM * BK / 4 / 256;   // float4 staging chunks (AMODE1)
    constexpr int AP4 = BM * BK / 8 / 256;   // us8 staging chunks (AMODE4)
    constexpr int BP = BN * BK / 8 / 256;    // us8 staging chunks (B)
    __shared__ alignas(16) unsigned short sA[BM * LDW];
    __shared__ alignas(16) unsigned short sB[BN * LDW];
    const int t = threadIdx.x;
    const int w = t >> 6, l = t & 63;
    const int wr = w / WN, wc = w % WN;
    const int m0 = blockIdx.x * BM;

    f32x4 acc[MF][NF] = {};

    for (int k0 = 0; k0 < K; k0 += BK) {
        if constexpr (AMODE == 1) {
            const float* A32 = (const float*)Aptr;
#pragma unroll
            for (int p = 0; p < AP1; ++p) {
                int flat = p * 256 + t;
                int row = flat >> 4, c4 = flat & 15;
                float4 v = *(const float4*)&A32[(size_t)(m0 + row) * K + k0 + c4 * 4];
                *(ushort4*)&sA[row * LDW + c4 * 4] =
                    make_ushort4(f2bf(v.x), f2bf(v.y), f2bf(v.z), f2bf(v.w));
            }
        } else {
            const unsigned short* A16 = (const unsigned short*)Aptr;
#pragma unroll
            for (int p = 0; p < AP4; ++p) {
                int flat = p * 256 + t;
                int row = flat >> 3, c8 = flat & 7;
                size_t base = (size_t)(m0 + row) * K + k0 + c8 * 8;
                float s[8] = {};
#pragma unroll
                for (int sl = 0; sl < 4; ++sl) {
                    us8 v = *(const us8*)&A16[(size_t)sl * aslab + base];
#pragma unroll
                    for (int e = 0; e < 8; ++e) s[e] += bf2f(v[e]);
                }
                us8 o;
#pragma unroll
                for (int e = 0; e < 8; ++e) o[e] = f2bf(fmaxf(s[e], 0.f));
                *(us8*)&sA[row * LDW + c8 * 8] = o;
            }
        }
#pragma unroll
        for (int p = 0; p < BP; ++p) {
            int flat = p * 256 + t;
            int row = flat >> 3, c8 = flat & 7;
            us8 v = *(const us8*)&BT[(size_t)row * K + k0 + c8 * 8];
            *(us8*)&sB[row * LDW + c8 * 8] = v;
        }
        __syncthreads();
#pragma unroll
        for (int kk = 0; kk < BK; kk += 32) {
            bf16x8 av[MF], bv[NF];
#pragma unroll
            for (int m = 0; m < MF; ++m)
                av[m] = *(const bf16x8*)&sA[(wr * (BM / WM) + m * 16 + (l & 15)) * LDW + kk + (l >> 4) * 8];
#pragma unroll
            for (int n = 0; n < NF; ++n)
                bv[n] = *(const bf16x8*)&sB[(wc * (BN / WN) + n * 16 + (l & 15)) * LDW + kk + (l >> 4) * 8];
#pragma unroll
            for (int m = 0; m < MF; ++m)
#pragma unroll
                for (int n = 0; n < NF; ++n)
                    acc[m][n] = __builtin_amdgcn_mfma_f32_16x16x32_bf16(av[m], bv[n], acc[m][n], 0, 0, 0);
        }
        __syncthreads();
    }

#pragma unroll
    for (int m = 0; m < MF; ++m) {
#pragma unroll
        for (int n = 0; n < NF; ++n) {
            const int col = wc * (BN / WN) + n * 16 + (l & 15);
            const int rb = m0 + wr * (BM / WM) + m * 16 + ((l >> 4) << 2);
            float v0 = acc[m][n][0], v1 = acc[m][n][1], v2 = acc[m][n][2], v3 = acc[m][n][3];
            if constexpr (TOUT) {
                ushort4 o = make_ushort4(f2bf(v0), f2bf(v1), f2bf(v2), f2bf(v3));
                *(ushort4*)((unsigned short*)C + (size_t)col * M + rb) = o;
            } else {
                C[(size_t)(rb + 0) * N + col] = (OutT)v0;
                C[(size_t)(rb + 1) * N + col] = (OutT)v1;
                C[(size_t)(rb + 2) * N + col] = (OutT)v2;
                C[(size_t)(rb + 3) * N + col] = (OutT)v3;
            }
        }
    }
}

// ---- big adj-streaming GEMM: reg-staged DEPTH-2 pipeline with STATIC register
// sets (rule #20), A+B LDS dbuf (B MUST route via LDS: R16 FIFO-vmcnt lesson),
// raw non-draining barrier, XCD swizzle. MINB = min BLOCKS/CU (R11 lesson).
// OUTBF: bf16 K-split partial slab (t1); o stays fp32.
// C slab z = adj[M][K] @ (BT[N][K])^T ----
template<int BM, int BN, int WM, int WN, int THREADS, int MINB, bool OUTBF>
__global__ __launch_bounds__(THREADS, MINB) void pipe_gemm_kernel(
    const float* __restrict__ A, const unsigned short* __restrict__ BT,
    void* __restrict__ Cout, int M, int N, int K) {
    constexpr int BK = 64, LDW = 72;
    constexpr int MF = BM / WM / 16, NF = BN / WN / 16;
    constexpr int ACH = BM * BK / 4 / THREADS;   // float4 per thread (A)
    constexpr int BCH = BN * BK / 8 / THREADS;   // us8 per thread (B)
    static_assert(ACH * THREADS * 4 == BM * BK && BCH * THREADS * 8 == BN * BK, "split");
    __shared__ alignas(16) unsigned short sA[2][BM * LDW];
    __shared__ alignas(16) unsigned short sB[2][BN * LDW];
    const int t = threadIdx.x, w = t >> 6, l = t & 63;
    const int wr = w / WN, wc = w % WN;
    // XCD-aware bijective remap (nwg % 8 == 0): each XCD gets a contiguous
    // chunk -> all its blocks share one K-slice (L2-resident B slice).
    const int nx = gridDim.x;
    const int lin = blockIdx.x + nx * blockIdx.z;
    const int cpx = (nx * gridDim.z) >> 3;
    const int sw = (lin & 7) * cpx + (lin >> 3);
    const int bx = sw % nx, bz = sw / nx;
    const int m0 = bx * BM;
    const int klen = K / gridDim.z, kbeg = bz * klen;
    const int NT = klen / BK;

    float4 a0[ACH], a1[ACH];     // two STATIC register sets (no runtime index)
    us8 b0[BCH], b1[BCH];

    auto LOAD = [&](float4 (&ar)[ACH], us8 (&br)[BCH], int k0) {
#pragma unroll
        for (int p = 0; p < ACH; ++p) {
            int flat = p * THREADS + t, row = flat >> 4, c4 = flat & 15;
            ar[p] = *(const float4*)&A[(size_t)(m0 + row) * K + k0 + c4 * 4];
        }
#pragma unroll
        for (int p = 0; p < BCH; ++p) {
            int flat = p * THREADS + t, row = flat >> 3, c8 = flat & 7;
            br[p] = *(const us8*)&BT[(size_t)row * K + k0 + c8 * 8];
        }
    };
    auto WRITE = [&](float4 (&ar)[ACH], us8 (&br)[BCH], int buf) {
#pragma unroll
        for (int p = 0; p < ACH; ++p) {
            int flat = p * THREADS + t, row = flat >> 4, c4 = flat & 15;
            float4 v = ar[p];
            *(ushort4*)&sA[buf][row * LDW + c4 * 4] =
                make_ushort4(f2bf(v.x), f2bf(v.y), f2bf(v.z), f2bf(v.w));
        }
#pragma unroll
        for (int p = 0; p < BCH; ++p) {
            int flat = p * THREADS + t, row = flat >> 3, c8 = flat & 7;
            *(us8*)&sB[buf][row * LDW + c8 * 8] = br[p];
        }
    };

    f32x4 acc[MF][NF] = {};

    auto COMPUTE = [&](int buf) {
#pragma unroll
        for (int kk = 0; kk < BK; kk += 32) {
            bf16x8 av[MF], bv[NF];
#pragma unroll
            for (int m = 0; m < MF; ++m)
                av[m] = *(const bf16x8*)&sA[buf][(wr * (BM / WM) + m * 16 + (l & 15)) * LDW + kk + (l >> 4) * 8];
#pragma unroll
            for (int n = 0; n < NF; ++n)
                bv[n] = *(const bf16x8*)&sB[buf][(wc * (BN / WN) + n * 16 + (l & 15)) * LDW + kk + (l >> 4) * 8];
#pragma unroll
            for (int m = 0; m < MF; ++m)
#pragma unroll
                for (int n = 0; n < NF; ++n)
                    acc[m][n] = __builtin_amdgcn_mfma_f32_16x16x32_bf16(av[m], bv[n], acc[m][n], 0, 0, 0);
        }
    };

    // prologue: tiles 0,1 in flight; tile 0 staged to LDS buf0
    LOAD(a0, b0, kbeg);
    LOAD(a1, b1, kbeg + BK);
    WRITE(a0, b0, 0);            // counted wait: only tile-1 loads outstanding
    hard_barrier();

    for (int tt = 0; tt < NT; tt += 2) {
        if (tt + 2 < NT) LOAD(a0, b0, kbeg + (tt + 2) * BK);
        __builtin_amdgcn_sched_barrier(0);
        COMPUTE(0);
        if (tt + 1 < NT) WRITE(a1, b1, 1);   // counted wait: tt+2 stays in flight
        hard_barrier();
        if (tt + 1 < NT) {
            if (tt + 3 < NT) LOAD(a1, b1, kbeg + (tt + 3) * BK);
            __builtin_amdgcn_sched_barrier(0);
            COMPUTE(1);
            if (tt + 2 < NT) WRITE(a0, b0, 0);
            hard_barrier();
        }
    }

#pragma unroll
    for (int m = 0; m < MF; ++m)
#pragma unroll
        for (int n = 0; n < NF; ++n) {
            const int col = wc * (BN / WN) + n * 16 + (l & 15);
            const int rb = m0 + wr * (BM / WM) + m * 16 + ((l >> 4) << 2);
#pragma unroll
            for (int j = 0; j < 4; ++j) {
                if constexpr (OUTBF)
                    ((unsigned short*)Cout)[(size_t)bz * M * N + (size_t)(rb + j) * N + col] =
                        f2bf(acc[m][n][j]);
                else
                    ((float*)Cout)[(size_t)bz * M * N + (size_t)(rb + j) * N + col] =
                        acc[m][n][j];
            }
        }
}

// ---- head: reduce 4 fp32 partial slabs of o[8192][64], then log_softmax rows ----
__global__ __launch_bounds__(256) void head2_kernel(
    const float* __restrict__ p, float* __restrict__ out, int M) {
    const int t = threadIdx.x, w = t >> 6, l = t & 63;
    const size_t stride = (size_t)M * 64;
#pragma unroll
    for (int rr = 0; rr < 4; ++rr) {
        int i = blockIdx.x * 16 + w * 4 + rr;
        size_t off = (size_t)i * 64 + l;
        float v = 0.f;
#pragma unroll
        for (int s = 0; s < 4; ++s) v += p[s * stride + off];
        float mx = v;
#pragma unroll
        for (int o = 32; o; o >>= 1) mx = fmaxf(mx, __shfl_xor(mx, o));
        float d0 = v - mx;
        float e = __expf(d0);
#pragma unroll
        for (int o = 32; o; o >>= 1) e += __shfl_xor(e, o);
        out[off] = d0 - __logf(e);
    }
}

extern "C" void kernel_launch(void* const* d_in, const int* in_sizes, int n_in,
                              void* d_out, int out_size, void* d_ws, size_t ws_size,
                              hipStream_t stream) {
    const float* adj = (const float*)d_in[0];
    const float* x   = (const float*)d_in[1];
    const float* W1  = (const float*)d_in[2];
    const float* W2  = (const float*)d_in[3];
    float* out = (float*)d_out;

    const int M = 8192, K = 8192;
    char* ws = (char*)d_ws;
    // ws layout (~30 MB; ws_size ~1 GB):
    unsigned short* pbuf1 = (unsigned short*)ws;               // 16 MB: 4 bf16 slabs t1 partials [8192][256]
    float*          pbuf2 = (float*)(ws + 16777216);           //  8 MB: 4 fp32 slabs o partials [8192][64]
    unsigned short* zT    = (unsigned short*)(ws + 25165824);  //  4 MB: z^T  bf16 [256][8192]
    unsigned short* hwT   = (unsigned short*)(ws + 29360128);  //  1 MB: hw^T bf16 [64][8192]
    unsigned short* W1T   = (unsigned short*)(ws + 30408704);  // 128 KB
    unsigned short* W2T   = (unsigned short*)(ws + 30539776);  // 32 KB

    // W1^T and W2^T in one launch
    transpose2_kernel<<<dim3(20), 256, 0, stream>>>(W1, W2, W1T, W2T);
    // z^T = (x @ W1)^T, bf16  (BM=32 -> 256 blocks = full chip)
    gemm_kernel<32, 256, 1, 4, 1, true, unsigned short>
        <<<dim3(M / 32), 256, 0, stream>>>(x, W1T, zT, M, 256, 256, 0);
    // t1 partials (bf16, 4 slabs) = adj @ z  (K-split 4; defended best config)
    pipe_gemm_kernel<128, 256, 4, 4, 1024, 1, true>
        <<<dim3(M / 128, 1, 4), 1024, 0, stream>>>(adj, zT, pbuf1, M, 256, K);
    // hw^T = (relu(sum of 4 bf16 t1 slabs) @ W2)^T, bf16  (full chip)
    gemm_kernel<32, 64, 1, 4, 4, true, unsigned short>
        <<<dim3(M / 32), 256, 0, stream>>>(pbuf1, W2T, hwT, M, 64, 256, (long)M * 256);
    // o partials (fp32, 4 slabs) = adj @ hw
    // EXPERIMENT: K-split 8->4 (256 blocks, 8 waves, 1 block/CU, MINB=1)
    // halves the o-partial round-trip (16+16 -> 8+8 MB)
    pipe_gemm_kernel<128, 64, 4, 2, 512, 1, false>
        <<<dim3(M / 128, 1, 4), 512, 0, stream>>>(adj, hwT, pbuf2, M, 64, K);
    head2_kernel<<<dim3(M / 16), 256, 0, stream>>>(pbuf2, out, M);
}

// Round 20
// 142.818 us; speedup vs baseline: 1.1155x; 1.1155x over previous
//
#include <hip/hip_runtime.h>

typedef short bf16x8 __attribute__((ext_vector_type(8)));
typedef float f32x4 __attribute__((ext_vector_type(4)));
typedef unsigned short us8 __attribute__((ext_vector_type(8)));

__device__ __forceinline__ unsigned short f2bf(float f) {
    unsigned int u = __float_as_uint(f);
    u += 0x7fffu + ((u >> 16) & 1u);   // round-to-nearest-even
    return (unsigned short)(u >> 16);
}
__device__ __forceinline__ float bf2f(unsigned short s) {
    return __uint_as_float((unsigned int)s << 16);
}

// raw barrier: does NOT drain vmcnt (in-flight global->VGPR loads survive);
// lgkmcnt(0) makes ds_writes visible; sched_barrier pins ordering (rule #18).
__device__ __forceinline__ void hard_barrier() {
    asm volatile("s_waitcnt lgkmcnt(0)" ::: "memory");
    __builtin_amdgcn_sched_barrier(0);
    __builtin_amdgcn_s_barrier();
    __builtin_amdgcn_sched_barrier(0);
}

// ---- transpose + cast fp32 -> bf16: body shared by the merged launcher ----
__device__ __forceinline__ void transpose_tile(
    const float* __restrict__ in, unsigned short* __restrict__ out,
    int R, int Cc, int r0, int c0, int t) {
    __shared__ alignas(16) unsigned short sT[64][65];
#pragma unroll
    for (int p = 0; p < 16; ++p) {
        int flat = p * 256 + t;
        int r = flat >> 6, c = flat & 63;
        sT[c][r] = f2bf(in[(size_t)(r0 + r) * Cc + (c0 + c)]);
    }
    __syncthreads();
#pragma unroll
    for (int p = 0; p < 16; ++p) {
        int flat = p * 256 + t;
        int c = flat >> 6, r = flat & 63;
        out[(size_t)(c0 + c) * R + (r0 + r)] = sT[c][r];
    }
}

// one launch transposes both W1 (256x256, 16 tiles) and W2 (256x64, 4 tiles)
__global__ __launch_bounds__(256) void transpose2_kernel(
    const float* __restrict__ W1, const float* __restrict__ W2,
    unsigned short* __restrict__ W1T, unsigned short* __restrict__ W2T) {
    const int bx = blockIdx.x, t = threadIdx.x;
    if (bx < 16) transpose_tile(W1, W1T, 256, 256, (bx & 3) * 64, (bx >> 2) * 64, t);
    else         transpose_tile(W2, W2T, 256, 64, (bx - 16) * 64, 0, t);
}

// ---- small MFMA GEMM (templated BM, 4 waves): C[M][N] = A[M][K] @ BT^T ----
// AMODE 1: A fp32 -> bf16 during staging.
// AMODE 4: A = relu(sum of 4 bf16 slabs, stride aslab elems) -> bf16 staging.
// TOUT: write bf16 transposed C[N][M].
// BM=32 -> grid 256 blocks = full chip (R18 lesson).
template<int BM, int BN, int WM, int WN, int AMODE, bool TOUT, typename OutT>
__global__ __launch_bounds__(256) void gemm_kernel(
    const void* __restrict__ Aptr, const unsigned short* __restrict__ BT,
    OutT* __restrict__ C, int M, int N, int K, long aslab) {
    constexpr int BK = 64, LDW = 72;
    constexpr int MF = BM / WM / 16;
    constexpr int NF = BN / WN / 16;
    constexpr int AP1 = BM * BK / 4 / 256;   // float4 staging chunks (AMODE1)
    constexpr int AP4 = BM * BK / 8 / 256;   // us8 staging chunks (AMODE4)
    constexpr int BP = BN * BK / 8 / 256;    // us8 staging chunks (B)
    __shared__ alignas(16) unsigned short sA[BM * LDW];
    __shared__ alignas(16) unsigned short sB[BN * LDW];
    const int t = threadIdx.x;
    const int w = t >> 6, l = t & 63;
    const int wr = w / WN, wc = w % WN;
    const int m0 = blockIdx.x * BM;

    f32x4 acc[MF][NF] = {};

    for (int k0 = 0; k0 < K; k0 += BK) {
        if constexpr (AMODE == 1) {
            const float* A32 = (const float*)Aptr;
#pragma unroll
            for (int p = 0; p < AP1; ++p) {
                int flat = p * 256 + t;
                int row = flat >> 4, c4 = flat & 15;
                float4 v = *(const float4*)&A32[(size_t)(m0 + row) * K + k0 + c4 * 4];
                *(ushort4*)&sA[row * LDW + c4 * 4] =
                    make_ushort4(f2bf(v.x), f2bf(v.y), f2bf(v.z), f2bf(v.w));
            }
        } else {
            const unsigned short* A16 = (const unsigned short*)Aptr;
#pragma unroll
            for (int p = 0; p < AP4; ++p) {
                int flat = p * 256 + t;
                int row = flat >> 3, c8 = flat & 7;
                size_t base = (size_t)(m0 + row) * K + k0 + c8 * 8;
                float s[8] = {};
#pragma unroll
                for (int sl = 0; sl < 4; ++sl) {
                    us8 v = *(const us8*)&A16[(size_t)sl * aslab + base];
#pragma unroll
                    for (int e = 0; e < 8; ++e) s[e] += bf2f(v[e]);
                }
                us8 o;
#pragma unroll
                for (int e = 0; e < 8; ++e) o[e] = f2bf(fmaxf(s[e], 0.f));
                *(us8*)&sA[row * LDW + c8 * 8] = o;
            }
        }
#pragma unroll
        for (int p = 0; p < BP; ++p) {
            int flat = p * 256 + t;
            int row = flat >> 3, c8 = flat & 7;
            us8 v = *(const us8*)&BT[(size_t)row * K + k0 + c8 * 8];
            *(us8*)&sB[row * LDW + c8 * 8] = v;
        }
        __syncthreads();
#pragma unroll
        for (int kk = 0; kk < BK; kk += 32) {
            bf16x8 av[MF], bv[NF];
#pragma unroll
            for (int m = 0; m < MF; ++m)
                av[m] = *(const bf16x8*)&sA[(wr * (BM / WM) + m * 16 + (l & 15)) * LDW + kk + (l >> 4) * 8];
#pragma unroll
            for (int n = 0; n < NF; ++n)
                bv[n] = *(const bf16x8*)&sB[(wc * (BN / WN) + n * 16 + (l & 15)) * LDW + kk + (l >> 4) * 8];
#pragma unroll
            for (int m = 0; m < MF; ++m)
#pragma unroll
                for (int n = 0; n < NF; ++n)
                    acc[m][n] = __builtin_amdgcn_mfma_f32_16x16x32_bf16(av[m], bv[n], acc[m][n], 0, 0, 0);
        }
        __syncthreads();
    }

#pragma unroll
    for (int m = 0; m < MF; ++m) {
#pragma unroll
        for (int n = 0; n < NF; ++n) {
            const int col = wc * (BN / WN) + n * 16 + (l & 15);
            const int rb = m0 + wr * (BM / WM) + m * 16 + ((l >> 4) << 2);
            float v0 = acc[m][n][0], v1 = acc[m][n][1], v2 = acc[m][n][2], v3 = acc[m][n][3];
            if constexpr (TOUT) {
                ushort4 o = make_ushort4(f2bf(v0), f2bf(v1), f2bf(v2), f2bf(v3));
                *(ushort4*)((unsigned short*)C + (size_t)col * M + rb) = o;
            } else {
                C[(size_t)(rb + 0) * N + col] = (OutT)v0;
                C[(size_t)(rb + 1) * N + col] = (OutT)v1;
                C[(size_t)(rb + 2) * N + col] = (OutT)v2;
                C[(size_t)(rb + 3) * N + col] = (OutT)v3;
            }
        }
    }
}

// ---- big adj-streaming GEMM: reg-staged DEPTH-2 pipeline with STATIC register
// sets (rule #20), A+B LDS dbuf (B MUST route via LDS: R16 FIFO-vmcnt lesson),
// raw non-draining barrier, XCD swizzle. MINB = min BLOCKS/CU (R11 lesson).
// OUTBF: bf16 K-split partial slab (t1); o stays fp32.
// C slab z = adj[M][K] @ (BT[N][K])^T ----
template<int BM, int BN, int WM, int WN, int THREADS, int MINB, bool OUTBF>
__global__ __launch_bounds__(THREADS, MINB) void pipe_gemm_kernel(
    const float* __restrict__ A, const unsigned short* __restrict__ BT,
    void* __restrict__ Cout, int M, int N, int K) {
    constexpr int BK = 64, LDW = 72;
    constexpr int MF = BM / WM / 16, NF = BN / WN / 16;
    constexpr int ACH = BM * BK / 4 / THREADS;   // float4 per thread (A)
    constexpr int BCH = BN * BK / 8 / THREADS;   // us8 per thread (B)
    static_assert(ACH * THREADS * 4 == BM * BK && BCH * THREADS * 8 == BN * BK, "split");
    __shared__ alignas(16) unsigned short sA[2][BM * LDW];
    __shared__ alignas(16) unsigned short sB[2][BN * LDW];
    const int t = threadIdx.x, w = t >> 6, l = t & 63;
    const int wr = w / WN, wc = w % WN;
    // XCD-aware bijective remap (nwg % 8 == 0): each XCD gets a contiguous
    // chunk -> all its blocks share one K-slice (L2-resident B slice).
    const int nx = gridDim.x;
    const int lin = blockIdx.x + nx * blockIdx.z;
    const int cpx = (nx * gridDim.z) >> 3;
    const int sw = (lin & 7) * cpx + (lin >> 3);
    const int bx = sw % nx, bz = sw / nx;
    const int m0 = bx * BM;
    const int klen = K / gridDim.z, kbeg = bz * klen;
    const int NT = klen / BK;

    float4 a0[ACH], a1[ACH];     // two STATIC register sets (no runtime index)
    us8 b0[BCH], b1[BCH];

    auto LOAD = [&](float4 (&ar)[ACH], us8 (&br)[BCH], int k0) {
#pragma unroll
        for (int p = 0; p < ACH; ++p) {
            int flat = p * THREADS + t, row = flat >> 4, c4 = flat & 15;
            ar[p] = *(const float4*)&A[(size_t)(m0 + row) * K + k0 + c4 * 4];
        }
#pragma unroll
        for (int p = 0; p < BCH; ++p) {
            int flat = p * THREADS + t, row = flat >> 3, c8 = flat & 7;
            br[p] = *(const us8*)&BT[(size_t)row * K + k0 + c8 * 8];
        }
    };
    auto WRITE = [&](float4 (&ar)[ACH], us8 (&br)[BCH], int buf) {
#pragma unroll
        for (int p = 0; p < ACH; ++p) {
            int flat = p * THREADS + t, row = flat >> 4, c4 = flat & 15;
            float4 v = ar[p];
            *(ushort4*)&sA[buf][row * LDW + c4 * 4] =
                make_ushort4(f2bf(v.x), f2bf(v.y), f2bf(v.z), f2bf(v.w));
        }
#pragma unroll
        for (int p = 0; p < BCH; ++p) {
            int flat = p * THREADS + t, row = flat >> 3, c8 = flat & 7;
            *(us8*)&sB[buf][row * LDW + c8 * 8] = br[p];
        }
    };

    f32x4 acc[MF][NF] = {};

    auto COMPUTE = [&](int buf) {
#pragma unroll
        for (int kk = 0; kk < BK; kk += 32) {
            bf16x8 av[MF], bv[NF];
#pragma unroll
            for (int m = 0; m < MF; ++m)
                av[m] = *(const bf16x8*)&sA[buf][(wr * (BM / WM) + m * 16 + (l & 15)) * LDW + kk + (l >> 4) * 8];
#pragma unroll
            for (int n = 0; n < NF; ++n)
                bv[n] = *(const bf16x8*)&sB[buf][(wc * (BN / WN) + n * 16 + (l & 15)) * LDW + kk + (l >> 4) * 8];
#pragma unroll
            for (int m = 0; m < MF; ++m)
#pragma unroll
                for (int n = 0; n < NF; ++n)
                    acc[m][n] = __builtin_amdgcn_mfma_f32_16x16x32_bf16(av[m], bv[n], acc[m][n], 0, 0, 0);
        }
    };

    // prologue: tiles 0,1 in flight; tile 0 staged to LDS buf0
    LOAD(a0, b0, kbeg);
    LOAD(a1, b1, kbeg + BK);
    WRITE(a0, b0, 0);            // counted wait: only tile-1 loads outstanding
    hard_barrier();

    for (int tt = 0; tt < NT; tt += 2) {
        if (tt + 2 < NT) LOAD(a0, b0, kbeg + (tt + 2) * BK);
        __builtin_amdgcn_sched_barrier(0);
        COMPUTE(0);
        if (tt + 1 < NT) WRITE(a1, b1, 1);   // counted wait: tt+2 stays in flight
        hard_barrier();
        if (tt + 1 < NT) {
            if (tt + 3 < NT) LOAD(a1, b1, kbeg + (tt + 3) * BK);
            __builtin_amdgcn_sched_barrier(0);
            COMPUTE(1);
            if (tt + 2 < NT) WRITE(a0, b0, 0);
            hard_barrier();
        }
    }

#pragma unroll
    for (int m = 0; m < MF; ++m)
#pragma unroll
        for (int n = 0; n < NF; ++n) {
            const int col = wc * (BN / WN) + n * 16 + (l & 15);
            const int rb = m0 + wr * (BM / WM) + m * 16 + ((l >> 4) << 2);
#pragma unroll
            for (int j = 0; j < 4; ++j) {
                if constexpr (OUTBF)
                    ((unsigned short*)Cout)[(size_t)bz * M * N + (size_t)(rb + j) * N + col] =
                        f2bf(acc[m][n][j]);
                else
                    ((float*)Cout)[(size_t)bz * M * N + (size_t)(rb + j) * N + col] =
                        acc[m][n][j];
            }
        }
}

// ---- head: reduce 8 fp32 partial slabs of o[8192][64], then log_softmax rows ----
__global__ __launch_bounds__(256) void head2_kernel(
    const float* __restrict__ p, float* __restrict__ out, int M) {
    const int t = threadIdx.x, w = t >> 6, l = t & 63;
    const size_t stride = (size_t)M * 64;
#pragma unroll
    for (int rr = 0; rr < 4; ++rr) {
        int i = blockIdx.x * 16 + w * 4 + rr;
        size_t off = (size_t)i * 64 + l;
        float v = 0.f;
#pragma unroll
        for (int s = 0; s < 8; ++s) v += p[s * stride + off];
        float mx = v;
#pragma unroll
        for (int o = 32; o; o >>= 1) mx = fmaxf(mx, __shfl_xor(mx, o));
        float d0 = v - mx;
        float e = __expf(d0);
#pragma unroll
        for (int o = 32; o; o >>= 1) e += __shfl_xor(e, o);
        out[off] = d0 - __logf(e);
    }
}

extern "C" void kernel_launch(void* const* d_in, const int* in_sizes, int n_in,
                              void* d_out, int out_size, void* d_ws, size_t ws_size,
                              hipStream_t stream) {
    const float* adj = (const float*)d_in[0];
    const float* x   = (const float*)d_in[1];
    const float* W1  = (const float*)d_in[2];
    const float* W2  = (const float*)d_in[3];
    float* out = (float*)d_out;

    const int M = 8192, K = 8192;
    char* ws = (char*)d_ws;
    // ws layout (~38 MB; ws_size ~1 GB):
    unsigned short* pbuf1 = (unsigned short*)ws;               // 16 MB: 4 bf16 slabs t1 partials [8192][256]
    float*          pbuf2 = (float*)(ws + 16777216);           // 16 MB: 8 fp32 slabs o partials [8192][64]
    unsigned short* zT    = (unsigned short*)(ws + 33554432);  //  4 MB: z^T  bf16 [256][8192]
    unsigned short* hwT   = (unsigned short*)(ws + 37748736);  //  1 MB: hw^T bf16 [64][8192]
    unsigned short* W1T   = (unsigned short*)(ws + 38797312);  // 128 KB
    unsigned short* W2T   = (unsigned short*)(ws + 38928384);  // 32 KB

    // W1^T and W2^T in one launch
    transpose2_kernel<<<dim3(20), 256, 0, stream>>>(W1, W2, W1T, W2T);
    // z^T = (x @ W1)^T, bf16  (BM=32 -> 256 blocks = full chip)
    gemm_kernel<32, 256, 1, 4, 1, true, unsigned short>
        <<<dim3(M / 32), 256, 0, stream>>>(x, W1T, zT, M, 256, 256, 0);
    // t1 partials (bf16, 4 slabs) = adj @ z  (K-split 4; defended best config)
    pipe_gemm_kernel<128, 256, 4, 4, 1024, 1, true>
        <<<dim3(M / 128, 1, 4), 1024, 0, stream>>>(adj, zT, pbuf1, M, 256, K);
    // hw^T = (relu(sum of 4 bf16 t1 slabs) @ W2)^T, bf16  (full chip)
    gemm_kernel<32, 64, 1, 4, 4, true, unsigned short>
        <<<dim3(M / 32), 256, 0, stream>>>(pbuf1, W2T, hwT, M, 64, 256, (long)M * 256);
    // o partials (fp32, 8 slabs) = adj @ hw  (K-split 8, 2 blocks/CU — R19
    // lesson: ks=4's 1 block/CU regressed 16 µs; TLP is load-bearing here)
    pipe_gemm_kernel<128, 64, 4, 2, 512, 2, false>
        <<<dim3(M / 128, 1, 8), 512, 0, stream>>>(adj, hwT, pbuf2, M, 64, K);
    head2_kernel<<<dim3(M / 16), 256, 0, stream>>>(pbuf2, out, M);
}